// Round 7
// baseline (212.577 us; speedup 1.0000x reference)
//
#include <hip/hip_runtime.h>

#define BLOCK    256
#define B_ROWS   131072
#define C_COLS   128
#define K_SEL    64
#define ROW_BYTES (C_COLS * 4)                   // 512

#define ROWS_PB   32
#define GRID_MAIN (B_ROWS / ROWS_PB)             // 4096
#define GRID_CMP  (B_ROWS / BLOCK)               // 512 (+1 block for w table)

// d_ws layout:
//   [0     ..   512) : float w[128]
//   [512   ..   516) : int   count (active rows)
//   [1024  .. 17408) : float partials[GRID_MAIN]
//   [65536 ..  +512K): int   rowids[B_ROWS]
#define WS_COUNT_OFF    512
#define WS_PARTIALS_OFF 1024
#define WS_ROWIDS_OFF   65536

__global__ void compact_and_w(const int* __restrict__ batch_mask,
                              const int* __restrict__ class_idx,
                              int* __restrict__ count,
                              int* __restrict__ rowids,
                              float* __restrict__ w)
{
    if (blockIdx.x == GRID_CMP) {        // last block builds the weight table
        if (threadIdx.x < C_COLS) {
            int c = threadIdx.x, cnt = 0;
            #pragma unroll
            for (int k = 0; k < K_SEL; ++k)
                cnt += (class_idx[k] == c) ? 1 : 0;
            w[c] = (float)cnt;
        }
        return;
    }
    const int row = blockIdx.x * BLOCK + threadIdx.x;
    const int m   = batch_mask[row] ? 1 : 0;
    const unsigned long long b = __ballot(m);
    const int lane   = threadIdx.x & 63;
    const int wcount = __popcll(b);
    const int prefix = __popcll(b & ((1ULL << lane) - 1ULL));
    int base = 0;
    if (lane == 0 && wcount) base = atomicAdd(count, wcount);
    base = __shfl(base, 0);
    if (m) rowids[base + prefix] = row;
}

__device__ __forceinline__ float fast_log(float x) {
    return __log2f(x) * 0.6931471805599453f;
}

__device__ __forceinline__ float per_elem_loss(float o, float oc, float y,
                                               float wc) {
    float sharp = (o > 0.5f) ? (o + (1.0f - o) * 0.25f)
                             : (o - o * 0.25f);
    float lo  = fmaxf(fast_log(o),        -100.0f);
    float l1o = fmaxf(fast_log(1.0f - o), -100.0f);
    float bce = -(y * lo + (1.0f - y) * l1o);
    float dp = o  - sharp;
    float dc = oc - sharp;
    return wc * (bce + dp * dp + dc * dc);
}

// fire-and-forget 16B/lane global->LDS stage (no result VGPRs, vmcnt-tracked)
__device__ __forceinline__ void stage16(const void* g, void* l) {
    __builtin_amdgcn_global_load_lds(
        (const __attribute__((address_space(1))) void*)g,
        (__attribute__((address_space(3))) void*)l, 16, 0, 0);
}

__global__ __launch_bounds__(BLOCK) void semi_loss_main(
    const float* __restrict__ out,
    const float* __restrict__ outc,
    const float* __restrict__ lab,
    const int*  __restrict__ count,
    const int*  __restrict__ rowids,
    const float* __restrict__ wtab,
    float* __restrict__ partials)
{
    __shared__ float sO[ROWS_PB * C_COLS];   // 16 KB each
    __shared__ float sC[ROWS_PB * C_COLS];
    __shared__ float sY[ROWS_PB * C_COLS];
    __shared__ int   srow[ROWS_PB];
    __shared__ float sval[ROWS_PB];

    const int nact = *count;
    const int base = blockIdx.x * ROWS_PB;
    if (base >= nact) {
        if (threadIdx.x == 0) partials[blockIdx.x] = 0.0f;
        return;
    }

    if (threadIdx.x < ROWS_PB) {
        int idx = base + threadIdx.x;
        int ok  = idx < nact;
        srow[threadIdx.x] = ok ? rowids[idx] : rowids[base];
        sval[threadIdx.x] = ok ? 1.0f : 0.0f;
    }
    __syncthreads();

    const int wave = threadIdx.x >> 6;
    const int lane = threadIdx.x & 63;
    const int sub  = lane >> 5;              // which of the chunk's 2 rows
    const int l16  = (lane & 31) * 16;       // byte offset within the row

    // 12 fire-and-forget stages per thread: 3 arrays x 4 chunks.
    // Chunk c covers rows 2c,2c+1 -> LDS bytes [c*1024, c*1024+1024).
    #pragma unroll
    for (int j = 0; j < 4; ++j) {
        const int    c   = wave * 4 + j;             // 0..15, wave-uniform
        const size_t rid = (size_t)srow[2 * c + sub];
        const size_t gof = rid * ROW_BYTES + l16;
        char* lO = (char*)sO + c * 1024;             // wave-uniform LDS base
        char* lC = (char*)sC + c * 1024;
        char* lY = (char*)sY + c * 1024;
        stage16((const char*)out  + gof, lO);
        stage16((const char*)outc + gof, lC);
        stage16((const char*)lab  + gof, lY);
    }
    __syncthreads();   // drains vmcnt: all staged data visible in LDS

    const int cq = threadIdx.x & 31;
    const float4 w4 = ((const float4*)wtab)[cq];

    float sum = 0.0f;
    #pragma unroll
    for (int i = 0; i < 4; ++i) {
        const int f   = i * 256 + threadIdx.x;   // float4 index 0..1023
        const int row = f >> 5;
        float4 o4  = ((const float4*)sO)[f];
        float4 oc4 = ((const float4*)sC)[f];
        float4 y4  = ((const float4*)sY)[f];
        float s = per_elem_loss(o4.x, oc4.x, y4.x, w4.x)
                + per_elem_loss(o4.y, oc4.y, y4.y, w4.y)
                + per_elem_loss(o4.z, oc4.z, y4.z, w4.z)
                + per_elem_loss(o4.w, oc4.w, y4.w, w4.w);
        sum += sval[row] * s;
    }

    #pragma unroll
    for (int off = 32; off > 0; off >>= 1)
        sum += __shfl_down(sum, off);

    __shared__ float ssum[BLOCK / 64];
    if (lane == 0) ssum[wave] = sum;
    __syncthreads();
    if (threadIdx.x == 0) {
        float s = 0.0f;
        #pragma unroll
        for (int i = 0; i < BLOCK / 64; ++i) s += ssum[i];
        partials[blockIdx.x] = s;
    }
}

__global__ __launch_bounds__(BLOCK) void semi_loss_reduce(
    const float* __restrict__ partials,
    const int*  __restrict__ count,
    float* __restrict__ outv)
{
    double s = 0.0;
    for (int i = threadIdx.x; i < GRID_MAIN; i += BLOCK)
        s += (double)partials[i];
    #pragma unroll
    for (int off = 32; off > 0; off >>= 1)
        s += __shfl_down(s, off);
    __shared__ double dsum[BLOCK / 64];
    int wave = threadIdx.x >> 6;
    int lane = threadIdx.x & 63;
    if (lane == 0) dsum[wave] = s;
    __syncthreads();
    if (threadIdx.x == 0) {
        double ts = 0.0;
        #pragma unroll
        for (int i = 0; i < BLOCK / 64; ++i) ts += dsum[i];
        int n = *count;
        outv[0] = (n > 0) ? (float)(ts / ((double)n * (double)K_SEL)) : 0.0f;
    }
}

extern "C" void kernel_launch(void* const* d_in, const int* in_sizes, int n_in,
                              void* d_out, int out_size, void* d_ws, size_t ws_size,
                              hipStream_t stream) {
    const float* out_p  = (const float*)d_in[0];
    const float* outc_p = (const float*)d_in[1];
    const float* lab_p  = (const float*)d_in[2];
    const int*   cidx_p = (const int*)d_in[3];
    const int*   mask_p = (const int*)d_in[4];

    float* wtab     = (float*)d_ws;
    int*   count    = (int*)((char*)d_ws + WS_COUNT_OFF);
    float* partials = (float*)((char*)d_ws + WS_PARTIALS_OFF);
    int*   rowids   = (int*)((char*)d_ws + WS_ROWIDS_OFF);

    hipMemsetAsync(count, 0, sizeof(int), stream);
    compact_and_w<<<GRID_CMP + 1, BLOCK, 0, stream>>>(mask_p, cidx_p,
                                                      count, rowids, wtab);
    semi_loss_main<<<GRID_MAIN, BLOCK, 0, stream>>>(out_p, outc_p, lab_p,
                                                    count, rowids, wtab,
                                                    partials);
    semi_loss_reduce<<<1, BLOCK, 0, stream>>>(partials, count, (float*)d_out);
}

// Round 8
// 210.271 us; speedup vs baseline: 1.0110x; 1.0110x over previous
//
#include <hip/hip_runtime.h>

#define BLOCK    256
#define B_ROWS   131072
#define C_COLS   128
#define K_SEL    64
#define F4_PER_ROW (C_COLS / 4)                  // 32

#define GRID_MAIN 2048                           // persistent, 8 blocks/CU
#define NT        (GRID_MAIN * BLOCK)            // 524288 threads (mult of 32)
#define GRID_CMP  (B_ROWS / BLOCK)               // 512 (+1 block for w table)

// d_ws layout:
//   [0     ..   512) : float w[128]
//   [512   ..   516) : int   count (active rows)
//   [1024  ..  9216) : float partials[GRID_MAIN]
//   [65536 ..  +512K): int   rowids[B_ROWS]
#define WS_COUNT_OFF    512
#define WS_PARTIALS_OFF 1024
#define WS_ROWIDS_OFF   65536

__global__ void compact_and_w(const int* __restrict__ batch_mask,
                              const int* __restrict__ class_idx,
                              int* __restrict__ count,
                              int* __restrict__ rowids,
                              float* __restrict__ w)
{
    if (blockIdx.x == GRID_CMP) {        // last block builds the weight table
        if (threadIdx.x < C_COLS) {
            int c = threadIdx.x, cnt = 0;
            #pragma unroll
            for (int k = 0; k < K_SEL; ++k)
                cnt += (class_idx[k] == c) ? 1 : 0;
            w[c] = (float)cnt;
        }
        return;
    }
    const int row = blockIdx.x * BLOCK + threadIdx.x;
    const int m   = batch_mask[row] ? 1 : 0;
    const unsigned long long b = __ballot(m);
    const int lane   = threadIdx.x & 63;
    const int wcount = __popcll(b);
    const int prefix = __popcll(b & ((1ULL << lane) - 1ULL));
    int base = 0;
    if (lane == 0 && wcount) base = atomicAdd(count, wcount);
    base = __shfl(base, 0);
    if (m) rowids[base + prefix] = row;
}

__device__ __forceinline__ float fast_log(float x) {
    return __log2f(x) * 0.6931471805599453f;
}

__device__ __forceinline__ float per_elem_loss(float o, float oc, float y,
                                               float wc) {
    float sharp = (o > 0.5f) ? (o + (1.0f - o) * 0.25f)
                             : (o - o * 0.25f);
    float lo  = fmaxf(fast_log(o),        -100.0f);
    float l1o = fmaxf(fast_log(1.0f - o), -100.0f);
    float bce = -(y * lo + (1.0f - y) * l1o);
    float dp = o  - sharp;
    float dc = oc - sharp;
    return wc * (bce + dp * dp + dc * dc);
}

// Persistent grid-stride stream over the compacted row space with depth-2
// software pipeline: iteration i+1's loads are live across iteration i's
// compute, so the scheduler cannot sink them to their uses.
__global__ __launch_bounds__(BLOCK) void semi_loss_main(
    const float* __restrict__ out,
    const float* __restrict__ outc,
    const float* __restrict__ lab,
    const int*  __restrict__ count,
    const int*  __restrict__ rowids,
    const float* __restrict__ wtab,
    float* __restrict__ partials)
{
    const int nact  = *count;
    const int total = nact * F4_PER_ROW;      // virtual float4 index space
    const int tid   = blockIdx.x * BLOCK + threadIdx.x;
    const int cq    = tid & 31;               // invariant under += NT
    const float4 w4 = ((const float4*)wtab)[cq];

    float sum = 0.0f;
    int u = tid;

    // prologue: prefetch iteration 0
    float4 pa, pb, pc;
    if (u < total) {
        int v = rowids[u >> 5] * F4_PER_ROW + cq;
        pa = ((const float4*)out )[v];
        pb = ((const float4*)outc)[v];
        pc = ((const float4*)lab )[v];
    }

    while (u < total) {
        const int un = u + NT;
        float4 na, nb, nc;
        if (un < total) {                     // prefetch next iteration
            int vn = rowids[un >> 5] * F4_PER_ROW + cq;
            na = ((const float4*)out )[vn];
            nb = ((const float4*)outc)[vn];
            nc = ((const float4*)lab )[vn];
        }
        sum += per_elem_loss(pa.x, pb.x, pc.x, w4.x)
             + per_elem_loss(pa.y, pb.y, pc.y, w4.y)
             + per_elem_loss(pa.z, pb.z, pc.z, w4.z)
             + per_elem_loss(pa.w, pb.w, pc.w, w4.w);
        pa = na; pb = nb; pc = nc;
        u = un;
    }

    #pragma unroll
    for (int off = 32; off > 0; off >>= 1)
        sum += __shfl_down(sum, off);

    __shared__ float ssum[BLOCK / 64];
    const int wave = threadIdx.x >> 6;
    const int lane = threadIdx.x & 63;
    if (lane == 0) ssum[wave] = sum;
    __syncthreads();
    if (threadIdx.x == 0) {
        float s = 0.0f;
        #pragma unroll
        for (int i = 0; i < BLOCK / 64; ++i) s += ssum[i];
        partials[blockIdx.x] = s;
    }
}

__global__ __launch_bounds__(BLOCK) void semi_loss_reduce(
    const float* __restrict__ partials,
    const int*  __restrict__ count,
    float* __restrict__ outv)
{
    double s = 0.0;
    for (int i = threadIdx.x; i < GRID_MAIN; i += BLOCK)
        s += (double)partials[i];
    #pragma unroll
    for (int off = 32; off > 0; off >>= 1)
        s += __shfl_down(s, off);
    __shared__ double dsum[BLOCK / 64];
    int wave = threadIdx.x >> 6;
    int lane = threadIdx.x & 63;
    if (lane == 0) dsum[wave] = s;
    __syncthreads();
    if (threadIdx.x == 0) {
        double ts = 0.0;
        #pragma unroll
        for (int i = 0; i < BLOCK / 64; ++i) ts += dsum[i];
        int n = *count;
        outv[0] = (n > 0) ? (float)(ts / ((double)n * (double)K_SEL)) : 0.0f;
    }
}

extern "C" void kernel_launch(void* const* d_in, const int* in_sizes, int n_in,
                              void* d_out, int out_size, void* d_ws, size_t ws_size,
                              hipStream_t stream) {
    const float* out_p  = (const float*)d_in[0];
    const float* outc_p = (const float*)d_in[1];
    const float* lab_p  = (const float*)d_in[2];
    const int*   cidx_p = (const int*)d_in[3];
    const int*   mask_p = (const int*)d_in[4];

    float* wtab     = (float*)d_ws;
    int*   count    = (int*)((char*)d_ws + WS_COUNT_OFF);
    float* partials = (float*)((char*)d_ws + WS_PARTIALS_OFF);
    int*   rowids   = (int*)((char*)d_ws + WS_ROWIDS_OFF);

    hipMemsetAsync(count, 0, sizeof(int), stream);
    compact_and_w<<<GRID_CMP + 1, BLOCK, 0, stream>>>(mask_p, cidx_p,
                                                      count, rowids, wtab);
    semi_loss_main<<<GRID_MAIN, BLOCK, 0, stream>>>(out_p, outc_p, lab_p,
                                                    count, rowids, wtab,
                                                    partials);
    semi_loss_reduce<<<1, BLOCK, 0, stream>>>(partials, count, (float*)d_out);
}